// Round 3
// baseline (726.099 us; speedup 1.0000x reference)
//
#include <hip/hip_runtime.h>

// ---------------------------------------------------------------------------
// TransformerBlock: conv1d frontend + GN, 2 layers of {LN, QKV, rel-pos attn,
// O-proj(+lscale resid), LN, FFN(relu)} on MI355X. bf16 MFMA compute, f32
// residual stream. Round 2 resubmit (rounds 0-1 = broker acquisition timeouts,
// kernel never ran). Structure: m97-class 128^2 GEMM + fused flash attention
// with rel-pos bias via extra Q@pk^T MFMA tile + LDS gather.
// ---------------------------------------------------------------------------

typedef unsigned short u16;
typedef __attribute__((ext_vector_type(8))) short bf16x8;   // 8 x bf16 (4 VGPR)
typedef __attribute__((ext_vector_type(4))) float f32x4;

#define GLD16(gp, lp) __builtin_amdgcn_global_load_lds( \
    (const __attribute__((address_space(1))) void*)(gp), \
    (__attribute__((address_space(3))) void*)(lp), 16, 0, 0)

__device__ __forceinline__ u16 f2bf(float f) {            // RNE f32->bf16
  unsigned u = __float_as_uint(f);
  u += 0x7fffu + ((u >> 16) & 1u);
  return (u16)(u >> 16);
}
__device__ __forceinline__ float bf2f(u16 s) {
  return __uint_as_float(((unsigned)s) << 16);
}

// ---------------- frontend: conv1d(1->512, k5, s2, p2) + relu ---------------
__global__ __launch_bounds__(256) void conv_front(
    const float* __restrict__ x, const float* __restrict__ cw,
    const float* __restrict__ cb, float* __restrict__ out) {
  int idx = blockIdx.x * 256 + threadIdx.x;     // ((b*1024+t)*512+c)
  int c = idx & 511;
  int bt = idx >> 9;
  int t = bt & 1023;
  int b = bt >> 10;
  const float* xp = x + b * 2048;
  float acc = cb[c];
#pragma unroll
  for (int k = 0; k < 5; ++k) {
    int xi = 2 * t + k - 2;
    float xv = (xi >= 0 && xi < 2048) ? xp[xi] : 0.f;
    acc = fmaf(xv, cw[c * 5 + k], acc);
  }
  out[idx] = fmaxf(acc, 0.f);
}

// per-batch sum / sumsq over (T,D) = 524288 elems, atomics into stats[b*2+{0,1}]
__global__ __launch_bounds__(256) void gn_stats(
    const float* __restrict__ conv, float* __restrict__ stats) {
  int b = blockIdx.y;
  const float* p = conv + (size_t)b * 524288 + blockIdx.x * 8192;
  float s = 0.f, q = 0.f;
#pragma unroll
  for (int i = 0; i < 8; ++i) {
    float4 v = *(const float4*)(p + i * 1024 + threadIdx.x * 4);
    s += v.x + v.y + v.z + v.w;
    q += v.x * v.x + v.y * v.y + v.z * v.z + v.w * v.w;
  }
#pragma unroll
  for (int d = 1; d < 64; d <<= 1) { s += __shfl_xor(s, d); q += __shfl_xor(q, d); }
  if ((threadIdx.x & 63) == 0) {
    atomicAdd(&stats[b * 2], s);
    atomicAdd(&stats[b * 2 + 1], q);
  }
}

// GroupNorm affine + write h (f32) + fused LN1 -> xn (bf16). 1 wave per row.
__global__ __launch_bounds__(256) void gn_ln(
    const float* __restrict__ conv, const float* __restrict__ stats,
    const float* __restrict__ gng, const float* __restrict__ gnb,
    const float* __restrict__ lng, const float* __restrict__ lnb,
    float* __restrict__ h, u16* __restrict__ xn) {
  const int row = blockIdx.x * 4 + (threadIdx.x >> 6);
  const int l = threadIdx.x & 63;
  const int b = row >> 10;
  float gm = stats[b * 2] * (1.f / 524288.f);
  float gv = stats[b * 2 + 1] * (1.f / 524288.f) - gm * gm;
  float grs = rsqrtf(gv + 1e-5f);
  const float* p = conv + (size_t)row * 512 + l * 8;
  float4 a4 = *(const float4*)p;
  float4 b4 = *(const float4*)(p + 4);
  float v[8] = {a4.x, a4.y, a4.z, a4.w, b4.x, b4.y, b4.z, b4.w};
#pragma unroll
  for (int e = 0; e < 8; ++e) {
    int c = l * 8 + e;
    v[e] = (v[e] - gm) * grs * gng[c] + gnb[c];
  }
  float* hp = h + (size_t)row * 512 + l * 8;
  *(float4*)hp = make_float4(v[0], v[1], v[2], v[3]);
  *(float4*)(hp + 4) = make_float4(v[4], v[5], v[6], v[7]);
  float s = 0.f, q = 0.f;
#pragma unroll
  for (int e = 0; e < 8; ++e) { s += v[e]; q += v[e] * v[e]; }
#pragma unroll
  for (int d = 1; d < 64; d <<= 1) { s += __shfl_xor(s, d); q += __shfl_xor(q, d); }
  float mean = s * (1.f / 512.f);
  float rs = rsqrtf(q * (1.f / 512.f) - mean * mean + 1e-5f);
  bf16x8 ov;
#pragma unroll
  for (int e = 0; e < 8; ++e) {
    int c = l * 8 + e;
    ov[e] = (short)f2bf((v[e] - mean) * rs * lng[c] + lnb[c]);
  }
  *(bf16x8*)(xn + (size_t)row * 512 + l * 8) = ov;
}

// plain LayerNorm rows of h (f32) -> bf16. 1 wave per row.
__global__ __launch_bounds__(256) void ln_rows(
    const float* __restrict__ in, const float* __restrict__ gg,
    const float* __restrict__ bb, u16* __restrict__ out) {
  const int row = blockIdx.x * 4 + (threadIdx.x >> 6);
  const int l = threadIdx.x & 63;
  const float* p = in + (size_t)row * 512 + l * 8;
  float4 a4 = *(const float4*)p;
  float4 b4 = *(const float4*)(p + 4);
  float v[8] = {a4.x, a4.y, a4.z, a4.w, b4.x, b4.y, b4.z, b4.w};
  float s = 0.f, q = 0.f;
#pragma unroll
  for (int e = 0; e < 8; ++e) { s += v[e]; q += v[e] * v[e]; }
#pragma unroll
  for (int d = 1; d < 64; d <<= 1) { s += __shfl_xor(s, d); q += __shfl_xor(q, d); }
  float mean = s * (1.f / 512.f);
  float rs = rsqrtf(q * (1.f / 512.f) - mean * mean + 1e-5f);
  bf16x8 ov;
#pragma unroll
  for (int e = 0; e < 8; ++e) {
    int c = l * 8 + e;
    ov[e] = (short)f2bf((v[e] - mean) * rs * gg[c] + bb[c]);
  }
  *(bf16x8*)(out + (size_t)row * 512 + l * 8) = ov;
}

// -------- weight convert: f32 (K x N) row-major -> bf16 (N x K) row-major ----
__global__ __launch_bounds__(256) void cvt_wt(
    const float* __restrict__ src, u16* __restrict__ dst, int N, int kshift) {
  int idx = blockIdx.x * 256 + threadIdx.x;
  int K = 1 << kshift;
  int n = idx >> kshift;
  int k = idx & (K - 1);
  if (n >= N) return;
  dst[idx] = f2bf(src[(size_t)k * N + n]);
}

__global__ void pack_qkv_bias(const float* __restrict__ bq, const float* __restrict__ bk,
                              const float* __restrict__ bv, float* __restrict__ dst) {
  int i = blockIdx.x * 256 + threadIdx.x;
  if (i < 512) dst[i] = bq[i];
  else if (i < 1024) dst[i] = bk[i - 512];
  else if (i < 1536) dst[i] = bv[i - 1024];
}

// pos table: pk[r][d] = clip(pe_k[r + 6977][d], +-5) for r = j-i+1023 in [0,2047)
__global__ void cvt_pk(const float* __restrict__ pe, u16* __restrict__ pkb) {
  int i = blockIdx.x * 256 + threadIdx.x;
  if (i >= 2047 * 64) return;
  float v = pe[i + 6977 * 64];
  v = fminf(fmaxf(v, -5.f), 5.f);
  pkb[i] = f2bf(v);
}

// V transpose: qkv v-section (B*T, 512) -> vT[(b*8+h)*64 + d][t] for coalesced
// global_load_lds of V^T tiles in attention.
__global__ __launch_bounds__(256) void transpV(
    const u16* __restrict__ qkv, u16* __restrict__ vT) {
  __shared__ short tile[64][72];
  const int tid = threadIdx.x;
  const int tt = blockIdx.x, bh = blockIdx.y;
  const int b = bh >> 3, h = bh & 7;
#pragma unroll
  for (int rr = 0; rr < 2; ++rr) {
    int trow = rr * 32 + (tid >> 3);
    bf16x8 v = *(const bf16x8*)(qkv + (size_t)(b * 1024 + tt * 64 + trow) * 1536 +
                                1024 + h * 64 + (tid & 7) * 8);
#pragma unroll
    for (int e = 0; e < 8; ++e) tile[trow][(tid & 7) * 8 + e] = v[e];
  }
  __syncthreads();
#pragma unroll
  for (int rr = 0; rr < 2; ++rr) {
    int d = rr * 32 + (tid >> 3);
    bf16x8 ov;
#pragma unroll
    for (int e = 0; e < 8; ++e) ov[e] = tile[(tid & 7) * 8 + e][d];
    *(bf16x8*)(vT + ((size_t)bh * 64 + d) * 1024 + tt * 64 + (tid & 7) * 8) = ov;
  }
}

// ---------------- GEMM: C(MxN) = A(MxK,bf16) @ W^T(NxK,bf16) + epilogue ------
// 128x128 tile, BK=32, 4 waves, 16x16x32 MFMA, double-buffered global_load_lds.
// EPI: 0 = bf16 out (+bias); 1 = bf16 relu out; 2 = f32 resid + v*scale;
//      3 = f32 resid + v
template <int EPI>
__global__ __launch_bounds__(256) void gemm128(
    const u16* __restrict__ A, const u16* __restrict__ Wt,
    const float* __restrict__ bias, const float* __restrict__ scl,
    const float* __restrict__ resid, float* __restrict__ outf,
    u16* __restrict__ outb, int N, int K) {
  __shared__ __attribute__((aligned(16))) u16 As[2][128 * 32];
  __shared__ __attribute__((aligned(16))) u16 Bs[2][128 * 32];
  const int tid = threadIdx.x;
  const int l = tid & 63, w = tid >> 6;
  const int g = l >> 4, r = l & 15;
  const int wr = w >> 1, wc = w & 1;
  const int m0 = blockIdx.y * 128, n0 = blockIdx.x * 128;

  const f32x4 fz = {0.f, 0.f, 0.f, 0.f};
  f32x4 acc[4][4];
#pragma unroll
  for (int i = 0; i < 4; ++i)
#pragma unroll
    for (int j = 0; j < 4; ++j) acc[i][j] = fz;

  const int nkt = K >> 5;
  const int arow = tid >> 2, acol = (tid & 3) * 8;
  const u16* aG = A + (size_t)(m0 + arow) * K + acol;
  const u16* bG = Wt + (size_t)(n0 + arow) * K + acol;

  auto stage = [&](int kt, int buf) {
    const u16* ga = aG + kt * 32;
    const u16* gb = bG + kt * 32;
    u16* la = &As[buf][tid * 8];
    u16* lb = &Bs[buf][tid * 8];
    GLD16(ga, la);
    GLD16(ga + (size_t)64 * K, la + 2048);
    GLD16(gb, lb);
    GLD16(gb + (size_t)64 * K, lb + 2048);
  };

  stage(0, 0);
  __syncthreads();
  for (int kt = 0; kt < nkt; ++kt) {
    const int cb = kt & 1;
    if (kt + 1 < nkt) stage(kt + 1, cb ^ 1);
    bf16x8 af[4], bfr[4];
#pragma unroll
    for (int mi = 0; mi < 4; ++mi)
      af[mi] = *(const bf16x8*)&As[cb][(wr * 64 + mi * 16 + r) * 32 + g * 8];
#pragma unroll
    for (int ni = 0; ni < 4; ++ni)
      bfr[ni] = *(const bf16x8*)&Bs[cb][(wc * 64 + ni * 16 + r) * 32 + g * 8];
#pragma unroll
    for (int mi = 0; mi < 4; ++mi)
#pragma unroll
      for (int ni = 0; ni < 4; ++ni)
        acc[mi][ni] = __builtin_amdgcn_mfma_f32_16x16x32_bf16(
            af[mi], bfr[ni], acc[mi][ni], 0, 0, 0);
    __syncthreads();   // drains vmcnt(0): next tile staged, cur reads done
  }

#pragma unroll
  for (int mi = 0; mi < 4; ++mi)
#pragma unroll
    for (int ni = 0; ni < 4; ++ni)
#pragma unroll
      for (int reg = 0; reg < 4; ++reg) {
        int gm = m0 + wr * 64 + mi * 16 + g * 4 + reg;
        int gn = n0 + wc * 64 + ni * 16 + r;
        float v = acc[mi][ni][reg] + bias[gn];
        size_t oi = (size_t)gm * N + gn;
        if constexpr (EPI == 0) outb[oi] = f2bf(v);
        else if constexpr (EPI == 1) outb[oi] = f2bf(fmaxf(v, 0.f));
        else if constexpr (EPI == 2) outf[oi] = resid[oi] + v * scl[gn];
        else outf[oi] = resid[oi] + v;
      }
}

// ---------------- fused flash attention with relative-position bias ---------
// Block: 256 thr (4 waves), one (b,h, 64-row i-block). Loop 16 j-tiles of 64.
// Per tile: S = Q@K^T + gather(M) where M[ii][rr] = Q@pk^T (rr = jj-ii+63).
// LDS rows are 128B -> XOR swizzle byte^=((row&7)<<4), source-side pre-swizzled
// for global_load_lds (rule 21).
__global__ __launch_bounds__(256) void attn64(
    const u16* __restrict__ qkv, const u16* __restrict__ vT,
    const u16* __restrict__ pkb, u16* __restrict__ o) {
  __shared__ __attribute__((aligned(16))) u16 Kt[64 * 64];
  __shared__ __attribute__((aligned(16))) u16 Vtt[64 * 64];   // V^T: [d][j]
  __shared__ __attribute__((aligned(16))) u16 Pkt[128 * 64];
  __shared__ __attribute__((aligned(16))) u16 Mt[64 * 128];   // bf16 M tile
  __shared__ __attribute__((aligned(16))) u16 Pt[64 * 64];

  const int tid = threadIdx.x, l = tid & 63, w = tid >> 6;
  const int g = l >> 4, r = l & 15;
  const int iblk = blockIdx.x, bh = blockIdx.y;
  const int b = bh >> 3, h = bh & 7;
  const int i0 = iblk * 64;

  // Q fragments straight from global (row-reused across all 16 j-tiles)
  bf16x8 aq[2];
  {
    const u16* qp = qkv + (size_t)(b * 1024 + i0 + w * 16 + r) * 1536 + h * 64 + g * 8;
    aq[0] = *(const bf16x8*)(qp);
    aq[1] = *(const bf16x8*)(qp + 32);
  }

  const f32x4 fz = {0.f, 0.f, 0.f, 0.f};
  float mrow[4], lpart[4];
  f32x4 oacc[4];
#pragma unroll
  for (int i = 0; i < 4; ++i) { mrow[i] = -1e30f; lpart[i] = 0.f; oacc[i] = fz; }

  for (int jt = 0; jt < 16; ++jt) {
    const int j0 = jt * 64;
    {
      const u16* kg = qkv + (size_t)(b * 1024 + j0) * 1536 + 512 + h * 64;
      const u16* vg = vT + (size_t)bh * 64 * 1024 + j0;
      const int rbase = j0 - i0 + 960;
#pragma unroll
      for (int rr = 0; rr < 2; ++rr) {
        int row = rr * 32 + (tid >> 3);
        int colb = ((tid & 7) * 16) ^ ((row & 7) << 4);
        GLD16(kg + (size_t)row * 1536 + (colb >> 1), Kt + rr * 2048 + tid * 8);
        GLD16(vg + (size_t)row * 1024 + (colb >> 1), Vtt + rr * 2048 + tid * 8);
      }
#pragma unroll
      for (int rr = 0; rr < 4; ++rr) {
        int row = rr * 32 + (tid >> 3);
        int colb = ((tid & 7) * 16) ^ ((row & 7) << 4);
        int gr = rbase + row;
        gr = gr < 0 ? 0 : (gr > 2046 ? 2046 : gr);
        GLD16(pkb + (size_t)gr * 64 + (colb >> 1), Pkt + rr * 2048 + tid * 8);
      }
    }
    __syncthreads();

    // QK^T
    f32x4 sacc[4];
#pragma unroll
    for (int cf = 0; cf < 4; ++cf) sacc[cf] = fz;
#pragma unroll
    for (int ks = 0; ks < 2; ++ks)
#pragma unroll
      for (int cf = 0; cf < 4; ++cf) {
        int row = cf * 16 + r;
        int colb = (ks * 64 + g * 16) ^ ((row & 7) << 4);
        bf16x8 bk = *(const bf16x8*)(Kt + row * 64 + (colb >> 1));
        sacc[cf] = __builtin_amdgcn_mfma_f32_16x16x32_bf16(aq[ks], bk, sacc[cf], 0, 0, 0);
      }

    // M tile (64 x 128) -> LDS (bf16); wave-private rows, no barrier needed
#pragma unroll
    for (int mf = 0; mf < 8; ++mf) {
      f32x4 macc = fz;
#pragma unroll
      for (int ks = 0; ks < 2; ++ks) {
        int row = mf * 16 + r;
        int colb = (ks * 64 + g * 16) ^ ((row & 7) << 4);
        bf16x8 bp = *(const bf16x8*)(Pkt + row * 64 + (colb >> 1));
        macc = __builtin_amdgcn_mfma_f32_16x16x32_bf16(aq[ks], bp, macc, 0, 0, 0);
      }
#pragma unroll
      for (int reg = 0; reg < 4; ++reg)
        Mt[(w * 16 + g * 4 + reg) * 128 + mf * 16 + r] = f2bf(macc[reg]);
    }

    // S assembly + online softmax (row = w*16 + g*4 + reg, col = cf*16 + r)
    float sv[4][4], pmax[4];
#pragma unroll
    for (int reg = 0; reg < 4; ++reg) pmax[reg] = -1e30f;
#pragma unroll
    for (int cf = 0; cf < 4; ++cf)
#pragma unroll
      for (int reg = 0; reg < 4; ++reg) {
        int ii = w * 16 + g * 4 + reg;
        int jj = cf * 16 + r;
        float s = (sacc[cf][reg] + bf2f(Mt[ii * 128 + jj - ii + 63])) * 0.125f;
        sv[cf][reg] = s;
        pmax[reg] = fmaxf(pmax[reg], s);
      }
#pragma unroll
    for (int d = 1; d < 16; d <<= 1)
#pragma unroll
      for (int reg = 0; reg < 4; ++reg)
        pmax[reg] = fmaxf(pmax[reg], __shfl_xor(pmax[reg], d));
#pragma unroll
    for (int reg = 0; reg < 4; ++reg) {
      float mnew = fmaxf(mrow[reg], pmax[reg]);
      float corr = __expf(mrow[reg] - mnew);
      mrow[reg] = mnew;
      lpart[reg] *= corr;
#pragma unroll
      for (int df = 0; df < 4; ++df) oacc[df][reg] *= corr;
      float ps = 0.f;
      int ii = w * 16 + g * 4 + reg;
#pragma unroll
      for (int cf = 0; cf < 4; ++cf) {
        float p = __expf(sv[cf][reg] - mnew);
        ps += p;
        int jj = cf * 16 + r;
        int colb = (jj * 2) ^ ((ii & 7) << 4);
        Pt[ii * 64 + (colb >> 1)] = f2bf(p);
      }
      lpart[reg] += ps;
    }

    // PV: O += P @ V  (A from Pt, B from V^T; wave-private P rows)
#pragma unroll
    for (int ks = 0; ks < 2; ++ks) {
      int prow = w * 16 + r;
      int pcolb = (ks * 64 + g * 16) ^ ((prow & 7) << 4);
      bf16x8 ap = *(const bf16x8*)(Pt + prow * 64 + (pcolb >> 1));
#pragma unroll
      for (int df = 0; df < 4; ++df) {
        int vrow = df * 16 + r;
        int vcolb = (ks * 64 + g * 16) ^ ((vrow & 7) << 4);
        bf16x8 bv = *(const bf16x8*)(Vtt + vrow * 64 + (vcolb >> 1));
        oacc[df] = __builtin_amdgcn_mfma_f32_16x16x32_bf16(ap, bv, oacc[df], 0, 0, 0);
      }
    }
    __syncthreads();   // all waves done reading Kt/Vtt/Pkt before re-stage
  }

#pragma unroll
  for (int d = 1; d < 16; d <<= 1)
#pragma unroll
    for (int reg = 0; reg < 4; ++reg) lpart[reg] += __shfl_xor(lpart[reg], d);
#pragma unroll
  for (int reg = 0; reg < 4; ++reg) {
    float inv = 1.f / lpart[reg];
    int ii = w * 16 + g * 4 + reg;
#pragma unroll
    for (int df = 0; df < 4; ++df)
      o[(size_t)(b * 1024 + i0 + ii) * 512 + h * 64 + df * 16 + r] =
          f2bf(oacc[df][reg] * inv);
  }
}

// ---------------------------------------------------------------------------
extern "C" void kernel_launch(void* const* d_in, const int* in_sizes, int n_in,
                              void* d_out, int out_size, void* d_ws, size_t ws_size,
                              hipStream_t stream) {
  (void)in_sizes; (void)n_in; (void)out_size;
  const float* x      = (const float*)d_in[0];
  const float* conv_w = (const float*)d_in[1];
  const float* conv_b = (const float*)d_in[2];
  const float* gn_g   = (const float*)d_in[3];
  const float* gn_b   = (const float*)d_in[4];
  const float* pe_k   = (const float*)d_in[5];
  const float* ln1_g  = (const float*)d_in[6];
  const float* ln1_b  = (const float*)d_in[7];
  const float* wq     = (const float*)d_in[8];
  const float* bq     = (const float*)d_in[9];
  const float* wk     = (const float*)d_in[10];
  const float* bk     = (const float*)d_in[11];
  const float* wv     = (const float*)d_in[12];
  const float* bv     = (const float*)d_in[13];
  const float* wo     = (const float*)d_in[14];
  const float* bo     = (const float*)d_in[15];
  const float* lsc    = (const float*)d_in[16];
  const float* ln2_g  = (const float*)d_in[17];
  const float* ln2_b  = (const float*)d_in[18];
  const float* w1     = (const float*)d_in[19];
  const float* b1     = (const float*)d_in[20];
  const float* w2     = (const float*)d_in[21];
  const float* b2     = (const float*)d_in[22];

  char* ws = (char*)d_ws;
  size_t off = 0;
  auto alloc = [&](size_t bytes) {
    char* p = ws + off;
    off = (off + bytes + 255) & ~(size_t)255;
    return p;
  };
  float* hbuf  = (float*)alloc((size_t)8192 * 512 * 4);
  u16* xn      = (u16*)alloc((size_t)8192 * 512 * 2);
  u16* qkvb    = (u16*)alloc((size_t)8192 * 1536 * 2);
  u16* vTb     = (u16*)alloc((size_t)64 * 64 * 1024 * 2);
  u16* ob      = (u16*)alloc((size_t)8192 * 512 * 2);
  u16* f1      = (u16*)alloc((size_t)8192 * 2048 * 2);
  float* stats = (float*)alloc(256);
  u16* wqkvb   = (u16*)alloc((size_t)2 * 1536 * 512 * 2);
  u16* wob     = (u16*)alloc((size_t)2 * 512 * 512 * 2);
  u16* w1b     = (u16*)alloc((size_t)2 * 2048 * 512 * 2);
  u16* w2b     = (u16*)alloc((size_t)2 * 512 * 2048 * 2);
  float* bqkv  = (float*)alloc(2 * 1536 * 4);
  u16* pkbuf   = (u16*)alloc(2047 * 64 * 2);
  if (off > ws_size) return;   // workspace too small -> clean validation fail
  // convb is only live before the layer loop; alias it onto f1 (32 MB >= 16 MB)
  float* convb = (float*)f1;

  hipMemsetAsync(stats, 0, 64, stream);

  for (int lyr = 0; lyr < 2; ++lyr) {
    const size_t wOff = (size_t)lyr * 262144;
    cvt_wt<<<1024, 256, 0, stream>>>(wq + wOff, wqkvb + (size_t)lyr * 786432, 512, 9);
    cvt_wt<<<1024, 256, 0, stream>>>(wk + wOff, wqkvb + (size_t)lyr * 786432 + 262144, 512, 9);
    cvt_wt<<<1024, 256, 0, stream>>>(wv + wOff, wqkvb + (size_t)lyr * 786432 + 524288, 512, 9);
    cvt_wt<<<1024, 256, 0, stream>>>(wo + wOff, wob + wOff, 512, 9);
    cvt_wt<<<4096, 256, 0, stream>>>(w1 + (size_t)lyr * 1048576, w1b + (size_t)lyr * 1048576, 2048, 9);
    cvt_wt<<<4096, 256, 0, stream>>>(w2 + (size_t)lyr * 1048576, w2b + (size_t)lyr * 1048576, 512, 11);
    pack_qkv_bias<<<6, 256, 0, stream>>>(bq + lyr * 512, bk + lyr * 512, bv + lyr * 512,
                                         bqkv + lyr * 1536);
  }
  cvt_pk<<<512, 256, 0, stream>>>(pe_k, pkbuf);

  conv_front<<<16384, 256, 0, stream>>>(x, conv_w, conv_b, convb);
  gn_stats<<<dim3(64, 8), 256, 0, stream>>>(convb, stats);
  gn_ln<<<2048, 256, 0, stream>>>(convb, stats, gn_g, gn_b, ln1_g, ln1_b, hbuf, xn);

  for (int lyr = 0; lyr < 2; ++lyr) {
    gemm128<0><<<dim3(12, 64), 256, 0, stream>>>(
        xn, wqkvb + (size_t)lyr * 786432, bqkv + lyr * 1536,
        nullptr, nullptr, nullptr, qkvb, 1536, 512);
    transpV<<<dim3(16, 64), 256, 0, stream>>>(qkvb, vTb);
    attn64<<<dim3(16, 64), 256, 0, stream>>>(qkvb, vTb, pkbuf, ob);
    gemm128<2><<<dim3(4, 64), 256, 0, stream>>>(
        ob, wob + (size_t)lyr * 262144, bo + lyr * 512,
        lsc + lyr * 512, hbuf, hbuf, nullptr, 512, 512);
    ln_rows<<<2048, 256, 0, stream>>>(hbuf, ln2_g + lyr * 512, ln2_b + lyr * 512, xn);
    gemm128<1><<<dim3(16, 64), 256, 0, stream>>>(
        xn, w1b + (size_t)lyr * 1048576, b1 + lyr * 2048,
        nullptr, nullptr, nullptr, f1, 2048, 512);
    float* outp = (lyr == 1) ? (float*)d_out : hbuf;
    gemm128<3><<<dim3(4, 64), 256, 0, stream>>>(
        f1, w2b + (size_t)lyr * 1048576, b2 + lyr * 512,
        nullptr, hbuf, outp, nullptr, 512, 2048);
    if (lyr == 0)
      ln_rows<<<2048, 256, 0, stream>>>(hbuf, ln1_g + 512, ln1_b + 512, xn);
  }
}

// Round 4
// 661.019 us; speedup vs baseline: 1.0985x; 1.0985x over previous
//
#include <hip/hip_runtime.h>

// ---------------------------------------------------------------------------
// TransformerBlock on MI355X. Round 4: attn64 LDS 56->40KB by aliasing the
// M-tile onto Pkt's storage (macc held in regs across a barrier) -> 4 blocks/CU
// (was 2). Merged per-layer weight-convert launches (13 -> 8 prep kernels).
// ---------------------------------------------------------------------------

typedef unsigned short u16;
typedef __attribute__((ext_vector_type(8))) short bf16x8;   // 8 x bf16 (4 VGPR)
typedef __attribute__((ext_vector_type(4))) float f32x4;

#define GLD16(gp, lp) __builtin_amdgcn_global_load_lds( \
    (const __attribute__((address_space(1))) void*)(gp), \
    (__attribute__((address_space(3))) void*)(lp), 16, 0, 0)

__device__ __forceinline__ u16 f2bf(float f) {            // RNE f32->bf16
  unsigned u = __float_as_uint(f);
  u += 0x7fffu + ((u >> 16) & 1u);
  return (u16)(u >> 16);
}
__device__ __forceinline__ float bf2f(u16 s) {
  return __uint_as_float(((unsigned)s) << 16);
}

// ---------------- frontend: conv1d(1->512, k5, s2, p2) + relu ---------------
__global__ __launch_bounds__(256) void conv_front(
    const float* __restrict__ x, const float* __restrict__ cw,
    const float* __restrict__ cb, float* __restrict__ out) {
  int idx = blockIdx.x * 256 + threadIdx.x;     // ((b*1024+t)*512+c)
  int c = idx & 511;
  int bt = idx >> 9;
  int t = bt & 1023;
  int b = bt >> 10;
  const float* xp = x + b * 2048;
  float acc = cb[c];
#pragma unroll
  for (int k = 0; k < 5; ++k) {
    int xi = 2 * t + k - 2;
    float xv = (xi >= 0 && xi < 2048) ? xp[xi] : 0.f;
    acc = fmaf(xv, cw[c * 5 + k], acc);
  }
  out[idx] = fmaxf(acc, 0.f);
}

// per-batch sum / sumsq over (T,D) = 524288 elems, atomics into stats[b*2+{0,1}]
__global__ __launch_bounds__(256) void gn_stats(
    const float* __restrict__ conv, float* __restrict__ stats) {
  int b = blockIdx.y;
  const float* p = conv + (size_t)b * 524288 + blockIdx.x * 8192;
  float s = 0.f, q = 0.f;
#pragma unroll
  for (int i = 0; i < 8; ++i) {
    float4 v = *(const float4*)(p + i * 1024 + threadIdx.x * 4);
    s += v.x + v.y + v.z + v.w;
    q += v.x * v.x + v.y * v.y + v.z * v.z + v.w * v.w;
  }
#pragma unroll
  for (int d = 1; d < 64; d <<= 1) { s += __shfl_xor(s, d); q += __shfl_xor(q, d); }
  if ((threadIdx.x & 63) == 0) {
    atomicAdd(&stats[b * 2], s);
    atomicAdd(&stats[b * 2 + 1], q);
  }
}

// GroupNorm affine + write h (f32) + fused LN1 -> xn (bf16). 1 wave per row.
__global__ __launch_bounds__(256) void gn_ln(
    const float* __restrict__ conv, const float* __restrict__ stats,
    const float* __restrict__ gng, const float* __restrict__ gnb,
    const float* __restrict__ lng, const float* __restrict__ lnb,
    float* __restrict__ h, u16* __restrict__ xn) {
  const int row = blockIdx.x * 4 + (threadIdx.x >> 6);
  const int l = threadIdx.x & 63;
  const int b = row >> 10;
  float gm = stats[b * 2] * (1.f / 524288.f);
  float gv = stats[b * 2 + 1] * (1.f / 524288.f) - gm * gm;
  float grs = rsqrtf(gv + 1e-5f);
  const float* p = conv + (size_t)row * 512 + l * 8;
  float4 a4 = *(const float4*)p;
  float4 b4 = *(const float4*)(p + 4);
  float v[8] = {a4.x, a4.y, a4.z, a4.w, b4.x, b4.y, b4.z, b4.w};
#pragma unroll
  for (int e = 0; e < 8; ++e) {
    int c = l * 8 + e;
    v[e] = (v[e] - gm) * grs * gng[c] + gnb[c];
  }
  float* hp = h + (size_t)row * 512 + l * 8;
  *(float4*)hp = make_float4(v[0], v[1], v[2], v[3]);
  *(float4*)(hp + 4) = make_float4(v[4], v[5], v[6], v[7]);
  float s = 0.f, q = 0.f;
#pragma unroll
  for (int e = 0; e < 8; ++e) { s += v[e]; q += v[e] * v[e]; }
#pragma unroll
  for (int d = 1; d < 64; d <<= 1) { s += __shfl_xor(s, d); q += __shfl_xor(q, d); }
  float mean = s * (1.f / 512.f);
  float rs = rsqrtf(q * (1.f / 512.f) - mean * mean + 1e-5f);
  bf16x8 ov;
#pragma unroll
  for (int e = 0; e < 8; ++e) {
    int c = l * 8 + e;
    ov[e] = (short)f2bf((v[e] - mean) * rs * lng[c] + lnb[c]);
  }
  *(bf16x8*)(xn + (size_t)row * 512 + l * 8) = ov;
}

// plain LayerNorm rows of h (f32) -> bf16. 1 wave per row.
__global__ __launch_bounds__(256) void ln_rows(
    const float* __restrict__ in, const float* __restrict__ gg,
    const float* __restrict__ bb, u16* __restrict__ out) {
  const int row = blockIdx.x * 4 + (threadIdx.x >> 6);
  const int l = threadIdx.x & 63;
  const float* p = in + (size_t)row * 512 + l * 8;
  float4 a4 = *(const float4*)p;
  float4 b4 = *(const float4*)(p + 4);
  float v[8] = {a4.x, a4.y, a4.z, a4.w, b4.x, b4.y, b4.z, b4.w};
  float s = 0.f, q = 0.f;
#pragma unroll
  for (int e = 0; e < 8; ++e) { s += v[e]; q += v[e] * v[e]; }
#pragma unroll
  for (int d = 1; d < 64; d <<= 1) { s += __shfl_xor(s, d); q += __shfl_xor(q, d); }
  float mean = s * (1.f / 512.f);
  float rs = rsqrtf(q * (1.f / 512.f) - mean * mean + 1e-5f);
  bf16x8 ov;
#pragma unroll
  for (int e = 0; e < 8; ++e) {
    int c = l * 8 + e;
    ov[e] = (short)f2bf((v[e] - mean) * rs * gg[c] + bb[c]);
  }
  *(bf16x8*)(out + (size_t)row * 512 + l * 8) = ov;
}

// weight convert: f32 (K x N) row-major -> bf16 (N x K) row-major, per layer y
__global__ __launch_bounds__(256) void cvt_wt(
    const float* __restrict__ src, u16* __restrict__ dst, int N, int kshift,
    size_t src_lstride, size_t dst_lstride) {
  src += blockIdx.y * src_lstride;
  dst += blockIdx.y * dst_lstride;
  int idx = blockIdx.x * 256 + threadIdx.x;
  int K = 1 << kshift;
  int n = idx >> kshift;
  int k = idx & (K - 1);
  if (n >= N) return;
  dst[idx] = f2bf(src[(size_t)k * N + n]);
}

__global__ void pack_qkv_bias(const float* __restrict__ bq, const float* __restrict__ bk,
                              const float* __restrict__ bv, float* __restrict__ dst) {
  int lyr = blockIdx.y;
  int i = blockIdx.x * 256 + threadIdx.x;
  if (i < 512) dst[lyr * 1536 + i] = bq[lyr * 512 + i];
  else if (i < 1024) dst[lyr * 1536 + i] = bk[lyr * 512 + i - 512];
  else if (i < 1536) dst[lyr * 1536 + i] = bv[lyr * 512 + i - 1024];
}

// pos table: pk[r][d] = clip(pe_k[r + 6977][d], +-5) for r = j-i+1023 in [0,2047)
__global__ void cvt_pk(const float* __restrict__ pe, u16* __restrict__ pkb) {
  int i = blockIdx.x * 256 + threadIdx.x;
  if (i >= 2047 * 64) return;
  float v = pe[i + 6977 * 64];
  v = fminf(fmaxf(v, -5.f), 5.f);
  pkb[i] = f2bf(v);
}

// V transpose: qkv v-section (B*T, 512) -> vT[(b*8+h)*64 + d][t]
__global__ __launch_bounds__(256) void transpV(
    const u16* __restrict__ qkv, u16* __restrict__ vT) {
  __shared__ short tile[64][72];
  const int tid = threadIdx.x;
  const int tt = blockIdx.x, bh = blockIdx.y;
  const int b = bh >> 3, h = bh & 7;
#pragma unroll
  for (int rr = 0; rr < 2; ++rr) {
    int trow = rr * 32 + (tid >> 3);
    bf16x8 v = *(const bf16x8*)(qkv + (size_t)(b * 1024 + tt * 64 + trow) * 1536 +
                                1024 + h * 64 + (tid & 7) * 8);
#pragma unroll
    for (int e = 0; e < 8; ++e) tile[trow][(tid & 7) * 8 + e] = v[e];
  }
  __syncthreads();
#pragma unroll
  for (int rr = 0; rr < 2; ++rr) {
    int d = rr * 32 + (tid >> 3);
    bf16x8 ov;
#pragma unroll
    for (int e = 0; e < 8; ++e) ov[e] = tile[(tid & 7) * 8 + e][d];
    *(bf16x8*)(vT + ((size_t)bh * 64 + d) * 1024 + tt * 64 + (tid & 7) * 8) = ov;
  }
}

// ---------------- GEMM: C(MxN) = A(MxK,bf16) @ W^T(NxK,bf16) + epilogue ------
// 128x128 tile, BK=32, 4 waves, 16x16x32 MFMA, double-buffered global_load_lds.
// EPI: 0 = bf16 out (+bias); 1 = bf16 relu out; 2 = f32 resid + v*scale;
//      3 = f32 resid + v
template <int EPI>
__global__ __launch_bounds__(256) void gemm128(
    const u16* __restrict__ A, const u16* __restrict__ Wt,
    const float* __restrict__ bias, const float* __restrict__ scl,
    const float* __restrict__ resid, float* __restrict__ outf,
    u16* __restrict__ outb, int N, int K) {
  __shared__ __attribute__((aligned(16))) u16 As[2][128 * 32];
  __shared__ __attribute__((aligned(16))) u16 Bs[2][128 * 32];
  const int tid = threadIdx.x;
  const int l = tid & 63, w = tid >> 6;
  const int g = l >> 4, r = l & 15;
  const int wr = w >> 1, wc = w & 1;
  const int m0 = blockIdx.y * 128, n0 = blockIdx.x * 128;

  const f32x4 fz = {0.f, 0.f, 0.f, 0.f};
  f32x4 acc[4][4];
#pragma unroll
  for (int i = 0; i < 4; ++i)
#pragma unroll
    for (int j = 0; j < 4; ++j) acc[i][j] = fz;

  const int nkt = K >> 5;
  const int arow = tid >> 2, acol = (tid & 3) * 8;
  const u16* aG = A + (size_t)(m0 + arow) * K + acol;
  const u16* bG = Wt + (size_t)(n0 + arow) * K + acol;

  auto stage = [&](int kt, int buf) {
    const u16* ga = aG + kt * 32;
    const u16* gb = bG + kt * 32;
    u16* la = &As[buf][tid * 8];
    u16* lb = &Bs[buf][tid * 8];
    GLD16(ga, la);
    GLD16(ga + (size_t)64 * K, la + 2048);
    GLD16(gb, lb);
    GLD16(gb + (size_t)64 * K, lb + 2048);
  };

  stage(0, 0);
  __syncthreads();
  for (int kt = 0; kt < nkt; ++kt) {
    const int cb = kt & 1;
    if (kt + 1 < nkt) stage(kt + 1, cb ^ 1);
    bf16x8 af[4], bfr[4];
#pragma unroll
    for (int mi = 0; mi < 4; ++mi)
      af[mi] = *(const bf16x8*)&As[cb][(wr * 64 + mi * 16 + r) * 32 + g * 8];
#pragma unroll
    for (int ni = 0; ni < 4; ++ni)
      bfr[ni] = *(const bf16x8*)&Bs[cb][(wc * 64 + ni * 16 + r) * 32 + g * 8];
#pragma unroll
    for (int mi = 0; mi < 4; ++mi)
#pragma unroll
      for (int ni = 0; ni < 4; ++ni)
        acc[mi][ni] = __builtin_amdgcn_mfma_f32_16x16x32_bf16(
            af[mi], bfr[ni], acc[mi][ni], 0, 0, 0);
    __syncthreads();   // drains vmcnt(0): next tile staged, cur reads done
  }

#pragma unroll
  for (int mi = 0; mi < 4; ++mi)
#pragma unroll
    for (int ni = 0; ni < 4; ++ni)
#pragma unroll
      for (int reg = 0; reg < 4; ++reg) {
        int gm = m0 + wr * 64 + mi * 16 + g * 4 + reg;
        int gn = n0 + wc * 64 + ni * 16 + r;
        float v = acc[mi][ni][reg] + bias[gn];
        size_t oi = (size_t)gm * N + gn;
        if constexpr (EPI == 0) outb[oi] = f2bf(v);
        else if constexpr (EPI == 1) outb[oi] = f2bf(fmaxf(v, 0.f));
        else if constexpr (EPI == 2) outf[oi] = resid[oi] + v * scl[gn];
        else outf[oi] = resid[oi] + v;
      }
}

// ---------------- fused flash attention with relative-position bias ---------
// 4 waves, one (b,h, 64-row i-block); 16 j-tiles of 64. LDS arena = 40 KB ->
// 4 blocks/CU. Pk staging region is reused for the M tile (macc kept in regs
// across a barrier). LDS XOR swizzle byte^=((row&7)<<4), source-pre-swizzled
// for global_load_lds (rule 21).
__global__ __launch_bounds__(256, 4) void attn64(
    const u16* __restrict__ qkv, const u16* __restrict__ vT,
    const u16* __restrict__ pkb, u16* __restrict__ o) {
  __shared__ __attribute__((aligned(16))) u16 lds[20480];   // 40 KB
  u16* Kt   = lds;            // [64][64] swizzled   (8 KB)
  u16* Vtt  = lds + 4096;     // [64][64] swizzled   (8 KB)  V^T: [d][j]
  u16* PkMt = lds + 8192;     // stage: [128][64] swz Pk; after bar2: Mt[64][128] (16 KB)
  u16* Pt   = lds + 16384;    // [64][64] swizzled   (8 KB)

  const int tid = threadIdx.x, l = tid & 63, w = tid >> 6;
  const int g = l >> 4, r = l & 15;
  const int iblk = blockIdx.x, bh = blockIdx.y;
  const int b = bh >> 3, h = bh & 7;
  const int i0 = iblk * 64;

  // Q fragments straight from global (row-reused across all 16 j-tiles)
  bf16x8 aq[2];
  {
    const u16* qp = qkv + (size_t)(b * 1024 + i0 + w * 16 + r) * 1536 + h * 64 + g * 8;
    aq[0] = *(const bf16x8*)(qp);
    aq[1] = *(const bf16x8*)(qp + 32);
  }

  const f32x4 fz = {0.f, 0.f, 0.f, 0.f};
  float mrow[4], lpart[4];
  f32x4 oacc[4];
#pragma unroll
  for (int i = 0; i < 4; ++i) { mrow[i] = -1e30f; lpart[i] = 0.f; oacc[i] = fz; }

  for (int jt = 0; jt < 16; ++jt) {
    const int j0 = jt * 64;
    {
      const u16* kg = qkv + (size_t)(b * 1024 + j0) * 1536 + 512 + h * 64;
      const u16* vg = vT + (size_t)bh * 64 * 1024 + j0;
      const int rbase = j0 - i0 + 960;
#pragma unroll
      for (int rr = 0; rr < 2; ++rr) {
        int row = rr * 32 + (tid >> 3);
        int colb = ((tid & 7) * 16) ^ ((row & 7) << 4);
        GLD16(kg + (size_t)row * 1536 + (colb >> 1), Kt + rr * 2048 + tid * 8);
        GLD16(vg + (size_t)row * 1024 + (colb >> 1), Vtt + rr * 2048 + tid * 8);
      }
#pragma unroll
      for (int rr = 0; rr < 4; ++rr) {
        int row = rr * 32 + (tid >> 3);
        int colb = ((tid & 7) * 16) ^ ((row & 7) << 4);
        int gr = rbase + row;
        gr = gr < 0 ? 0 : (gr > 2046 ? 2046 : gr);
        GLD16(pkb + (size_t)gr * 64 + (colb >> 1), PkMt + rr * 2048 + tid * 8);
      }
    }
    __syncthreads();   // bar1: staged K/V/Pk visible

    // QK^T
    f32x4 sacc[4];
#pragma unroll
    for (int cf = 0; cf < 4; ++cf) sacc[cf] = fz;
#pragma unroll
    for (int ks = 0; ks < 2; ++ks)
#pragma unroll
      for (int cf = 0; cf < 4; ++cf) {
        int row = cf * 16 + r;
        int colb = (ks * 64 + g * 16) ^ ((row & 7) << 4);
        bf16x8 bk = *(const bf16x8*)(Kt + row * 64 + (colb >> 1));
        sacc[cf] = __builtin_amdgcn_mfma_f32_16x16x32_bf16(aq[ks], bk, sacc[cf], 0, 0, 0);
      }

    // M = Q @ Pk^T (64 x 128), accumulators stay in registers
    f32x4 macc[8];
#pragma unroll
    for (int mf = 0; mf < 8; ++mf) {
      macc[mf] = fz;
#pragma unroll
      for (int ks = 0; ks < 2; ++ks) {
        int row = mf * 16 + r;
        int colb = (ks * 64 + g * 16) ^ ((row & 7) << 4);
        bf16x8 bp = *(const bf16x8*)(PkMt + row * 64 + (colb >> 1));
        macc[mf] = __builtin_amdgcn_mfma_f32_16x16x32_bf16(aq[ks], bp, macc[mf], 0, 0, 0);
      }
    }
    __syncthreads();   // bar2: all waves done reading Pk -> region reusable as Mt

    // Mt[64][128] into the Pk region (wave-private rows; own-row reads only)
#pragma unroll
    for (int mf = 0; mf < 8; ++mf)
#pragma unroll
      for (int reg = 0; reg < 4; ++reg)
        PkMt[(w * 16 + g * 4 + reg) * 128 + mf * 16 + r] = f2bf(macc[mf][reg]);

    // S assembly + online softmax (row = w*16 + g*4 + reg, col = cf*16 + r)
    float sv[4][4], pmax[4];
#pragma unroll
    for (int reg = 0; reg < 4; ++reg) pmax[reg] = -1e30f;
#pragma unroll
    for (int cf = 0; cf < 4; ++cf)
#pragma unroll
      for (int reg = 0; reg < 4; ++reg) {
        int ii = w * 16 + g * 4 + reg;
        int jj = cf * 16 + r;
        float s = (sacc[cf][reg] + bf2f(PkMt[ii * 128 + jj - ii + 63])) * 0.125f;
        sv[cf][reg] = s;
        pmax[reg] = fmaxf(pmax[reg], s);
      }
#pragma unroll
    for (int d = 1; d < 16; d <<= 1)
#pragma unroll
      for (int reg = 0; reg < 4; ++reg)
        pmax[reg] = fmaxf(pmax[reg], __shfl_xor(pmax[reg], d));
#pragma unroll
    for (int reg = 0; reg < 4; ++reg) {
      float mnew = fmaxf(mrow[reg], pmax[reg]);
      float corr = __expf(mrow[reg] - mnew);
      mrow[reg] = mnew;
      lpart[reg] *= corr;
#pragma unroll
      for (int df = 0; df < 4; ++df) oacc[df][reg] *= corr;
      float ps = 0.f;
      int ii = w * 16 + g * 4 + reg;
#pragma unroll
      for (int cf = 0; cf < 4; ++cf) {
        float p = __expf(sv[cf][reg] - mnew);
        ps += p;
        int jj = cf * 16 + r;
        int colb = (jj * 2) ^ ((ii & 7) << 4);
        Pt[ii * 64 + (colb >> 1)] = f2bf(p);
      }
      lpart[reg] += ps;
    }

    // PV: O += P @ V  (A from Pt, B from V^T; wave-private P rows)
#pragma unroll
    for (int ks = 0; ks < 2; ++ks) {
      int prow = w * 16 + r;
      int pcolb = (ks * 64 + g * 16) ^ ((prow & 7) << 4);
      bf16x8 ap = *(const bf16x8*)(Pt + prow * 64 + (pcolb >> 1));
#pragma unroll
      for (int df = 0; df < 4; ++df) {
        int vrow = df * 16 + r;
        int vcolb = (ks * 64 + g * 16) ^ ((vrow & 7) << 4);
        bf16x8 bv = *(const bf16x8*)(Vtt + vrow * 64 + (vcolb >> 1));
        oacc[df] = __builtin_amdgcn_mfma_f32_16x16x32_bf16(ap, bv, oacc[df], 0, 0, 0);
      }
    }
    __syncthreads();   // bar3: Kt/Vtt reads + Mt gather done before re-stage
  }

#pragma unroll
  for (int d = 1; d < 16; d <<= 1)
#pragma unroll
    for (int reg = 0; reg < 4; ++reg) lpart[reg] += __shfl_xor(lpart[reg], d);
#pragma unroll
  for (int reg = 0; reg < 4; ++reg) {
    float inv = 1.f / lpart[reg];
    int ii = w * 16 + g * 4 + reg;
#pragma unroll
    for (int df = 0; df < 4; ++df)
      o[(size_t)(b * 1024 + i0 + ii) * 512 + h * 64 + df * 16 + r] =
          f2bf(oacc[df][reg] * inv);
  }
}

// ---------------------------------------------------------------------------
extern "C" void kernel_launch(void* const* d_in, const int* in_sizes, int n_in,
                              void* d_out, int out_size, void* d_ws, size_t ws_size,
                              hipStream_t stream) {
  (void)in_sizes; (void)n_in; (void)out_size;
  const float* x      = (const float*)d_in[0];
  const float* conv_w = (const float*)d_in[1];
  const float* conv_b = (const float*)d_in[2];
  const float* gn_g   = (const float*)d_in[3];
  const float* gn_b   = (const float*)d_in[4];
  const float* pe_k   = (const float*)d_in[5];
  const float* ln1_g  = (const float*)d_in[6];
  const float* ln1_b  = (const float*)d_in[7];
  const float* wq     = (const float*)d_in[8];
  const float* bq     = (const float*)d_in[9];
  const float* wk     = (const float*)d_in[10];
  const float* bk     = (const float*)d_in[11];
  const float* wv     = (const float*)d_in[12];
  const float* bv     = (const float*)d_in[13];
  const float* wo     = (const float*)d_in[14];
  const float* bo     = (const float*)d_in[15];
  const float* lsc    = (const float*)d_in[16];
  const float* ln2_g  = (const float*)d_in[17];
  const float* ln2_b  = (const float*)d_in[18];
  const float* w1     = (const float*)d_in[19];
  const float* b1     = (const float*)d_in[20];
  const float* w2     = (const float*)d_in[21];
  const float* b2     = (const float*)d_in[22];

  char* ws = (char*)d_ws;
  size_t off = 0;
  auto alloc = [&](size_t bytes) {
    char* p = ws + off;
    off = (off + bytes + 255) & ~(size_t)255;
    return p;
  };
  float* hbuf  = (float*)alloc((size_t)8192 * 512 * 4);
  u16* xn      = (u16*)alloc((size_t)8192 * 512 * 2);
  u16* qkvb    = (u16*)alloc((size_t)8192 * 1536 * 2);
  u16* vTb     = (u16*)alloc((size_t)64 * 64 * 1024 * 2);
  u16* ob      = (u16*)alloc((size_t)8192 * 512 * 2);
  u16* f1      = (u16*)alloc((size_t)8192 * 2048 * 2);
  float* stats = (float*)alloc(256);
  u16* wqkvb   = (u16*)alloc((size_t)2 * 1536 * 512 * 2);
  u16* wob     = (u16*)alloc((size_t)2 * 512 * 512 * 2);
  u16* w1b     = (u16*)alloc((size_t)2 * 2048 * 512 * 2);
  u16* w2b     = (u16*)alloc((size_t)2 * 512 * 2048 * 2);
  float* bqkv  = (float*)alloc(2 * 1536 * 4);
  u16* pkbuf   = (u16*)alloc(2047 * 64 * 2);
  if (off > ws_size) return;   // workspace too small -> clean validation fail
  // convb is only live before the layer loop; alias it onto f1 (32 MB >= 16 MB)
  float* convb = (float*)f1;

  hipMemsetAsync(stats, 0, 64, stream);

  // weight/bias converts (layer dim = blockIdx.y)
  cvt_wt<<<dim3(1024, 2), 256, 0, stream>>>(wq, wqkvb, 512, 9, 262144, 786432);
  cvt_wt<<<dim3(1024, 2), 256, 0, stream>>>(wk, wqkvb + 262144, 512, 9, 262144, 786432);
  cvt_wt<<<dim3(1024, 2), 256, 0, stream>>>(wv, wqkvb + 524288, 512, 9, 262144, 786432);
  cvt_wt<<<dim3(1024, 2), 256, 0, stream>>>(wo, wob, 512, 9, 262144, 262144);
  cvt_wt<<<dim3(4096, 2), 256, 0, stream>>>(w1, w1b, 2048, 9, 1048576, 1048576);
  cvt_wt<<<dim3(4096, 2), 256, 0, stream>>>(w2, w2b, 512, 11, 1048576, 1048576);
  pack_qkv_bias<<<dim3(6, 2), 256, 0, stream>>>(bq, bk, bv, bqkv);
  cvt_pk<<<512, 256, 0, stream>>>(pe_k, pkbuf);

  conv_front<<<16384, 256, 0, stream>>>(x, conv_w, conv_b, convb);
  gn_stats<<<dim3(64, 8), 256, 0, stream>>>(convb, stats);
  gn_ln<<<2048, 256, 0, stream>>>(convb, stats, gn_g, gn_b, ln1_g, ln1_b, hbuf, xn);

  for (int lyr = 0; lyr < 2; ++lyr) {
    gemm128<0><<<dim3(12, 64), 256, 0, stream>>>(
        xn, wqkvb + (size_t)lyr * 786432, bqkv + lyr * 1536,
        nullptr, nullptr, nullptr, qkvb, 1536, 512);
    transpV<<<dim3(16, 64), 256, 0, stream>>>(qkvb, vTb);
    attn64<<<dim3(16, 64), 256, 0, stream>>>(qkvb, vTb, pkbuf, ob);
    gemm128<2><<<dim3(4, 64), 256, 0, stream>>>(
        ob, wob + (size_t)lyr * 262144, bo + lyr * 512,
        lsc + lyr * 512, hbuf, hbuf, nullptr, 512, 512);
    ln_rows<<<2048, 256, 0, stream>>>(hbuf, ln2_g + lyr * 512, ln2_b + lyr * 512, xn);
    gemm128<1><<<dim3(16, 64), 256, 0, stream>>>(
        xn, w1b + (size_t)lyr * 1048576, b1 + lyr * 2048,
        nullptr, nullptr, nullptr, f1, 2048, 512);
    float* outp = (lyr == 1) ? (float*)d_out : hbuf;
    gemm128<3><<<dim3(4, 64), 256, 0, stream>>>(
        f1, w2b + (size_t)lyr * 1048576, b2 + lyr * 512,
        nullptr, hbuf, outp, nullptr, 512, 2048);
    if (lyr == 0)
      ln_rows<<<2048, 256, 0, stream>>>(hbuf, ln1_g + 512, ln1_b + 512, xn);
  }
}

// Round 5
// 625.147 us; speedup vs baseline: 1.1615x; 1.0574x over previous
//
#include <hip/hip_runtime.h>

// ---------------------------------------------------------------------------
// TransformerBlock on MI355X. Round 5:
//  - attn64: rel-pos M computed in 64-wide chunks with ping-pong reuse
//    (window advances 64/tile -> half the M MFMAs and Pk staging were
//    redundant). LDS stays 40KB (4 blocks/CU). Q pre-scaled by 1/sqrt(dk)
//    in the QKV GEMM epilogue.
//  - gemm: BN=64 tile variant for O-proj/FFN2 (was 256 blocks = 1/CU ->
//    512 blocks = 2/CU, 2 waves/SIMD).
// ---------------------------------------------------------------------------

typedef unsigned short u16;
typedef __attribute__((ext_vector_type(8))) short bf16x8;   // 8 x bf16 (4 VGPR)
typedef __attribute__((ext_vector_type(4))) float f32x4;

#define GLD16(gp, lp) __builtin_amdgcn_global_load_lds( \
    (const __attribute__((address_space(1))) void*)(gp), \
    (__attribute__((address_space(3))) void*)(lp), 16, 0, 0)

__device__ __forceinline__ u16 f2bf(float f) {            // RNE f32->bf16
  unsigned u = __float_as_uint(f);
  u += 0x7fffu + ((u >> 16) & 1u);
  return (u16)(u >> 16);
}
__device__ __forceinline__ float bf2f(u16 s) {
  return __uint_as_float(((unsigned)s) << 16);
}

// ---------------- frontend: conv1d(1->512, k5, s2, p2) + relu ---------------
__global__ __launch_bounds__(256) void conv_front(
    const float* __restrict__ x, const float* __restrict__ cw,
    const float* __restrict__ cb, float* __restrict__ out) {
  int idx = blockIdx.x * 256 + threadIdx.x;     // ((b*1024+t)*512+c)
  int c = idx & 511;
  int bt = idx >> 9;
  int t = bt & 1023;
  int b = bt >> 10;
  const float* xp = x + b * 2048;
  float acc = cb[c];
#pragma unroll
  for (int k = 0; k < 5; ++k) {
    int xi = 2 * t + k - 2;
    float xv = (xi >= 0 && xi < 2048) ? xp[xi] : 0.f;
    acc = fmaf(xv, cw[c * 5 + k], acc);
  }
  out[idx] = fmaxf(acc, 0.f);
}

// per-batch sum / sumsq over (T,D) = 524288 elems, atomics into stats[b*2+{0,1}]
__global__ __launch_bounds__(256) void gn_stats(
    const float* __restrict__ conv, float* __restrict__ stats) {
  int b = blockIdx.y;
  const float* p = conv + (size_t)b * 524288 + blockIdx.x * 8192;
  float s = 0.f, q = 0.f;
#pragma unroll
  for (int i = 0; i < 8; ++i) {
    float4 v = *(const float4*)(p + i * 1024 + threadIdx.x * 4);
    s += v.x + v.y + v.z + v.w;
    q += v.x * v.x + v.y * v.y + v.z * v.z + v.w * v.w;
  }
#pragma unroll
  for (int d = 1; d < 64; d <<= 1) { s += __shfl_xor(s, d); q += __shfl_xor(q, d); }
  if ((threadIdx.x & 63) == 0) {
    atomicAdd(&stats[b * 2], s);
    atomicAdd(&stats[b * 2 + 1], q);
  }
}

// GroupNorm affine + write h (f32) + fused LN1 -> xn (bf16). 1 wave per row.
__global__ __launch_bounds__(256) void gn_ln(
    const float* __restrict__ conv, const float* __restrict__ stats,
    const float* __restrict__ gng, const float* __restrict__ gnb,
    const float* __restrict__ lng, const float* __restrict__ lnb,
    float* __restrict__ h, u16* __restrict__ xn) {
  const int row = blockIdx.x * 4 + (threadIdx.x >> 6);
  const int l = threadIdx.x & 63;
  const int b = row >> 10;
  float gm = stats[b * 2] * (1.f / 524288.f);
  float gv = stats[b * 2 + 1] * (1.f / 524288.f) - gm * gm;
  float grs = rsqrtf(gv + 1e-5f);
  const float* p = conv + (size_t)row * 512 + l * 8;
  float4 a4 = *(const float4*)p;
  float4 b4 = *(const float4*)(p + 4);
  float v[8] = {a4.x, a4.y, a4.z, a4.w, b4.x, b4.y, b4.z, b4.w};
#pragma unroll
  for (int e = 0; e < 8; ++e) {
    int c = l * 8 + e;
    v[e] = (v[e] - gm) * grs * gng[c] + gnb[c];
  }
  float* hp = h + (size_t)row * 512 + l * 8;
  *(float4*)hp = make_float4(v[0], v[1], v[2], v[3]);
  *(float4*)(hp + 4) = make_float4(v[4], v[5], v[6], v[7]);
  float s = 0.f, q = 0.f;
#pragma unroll
  for (int e = 0; e < 8; ++e) { s += v[e]; q += v[e] * v[e]; }
#pragma unroll
  for (int d = 1; d < 64; d <<= 1) { s += __shfl_xor(s, d); q += __shfl_xor(q, d); }
  float mean = s * (1.f / 512.f);
  float rs = rsqrtf(q * (1.f / 512.f) - mean * mean + 1e-5f);
  bf16x8 ov;
#pragma unroll
  for (int e = 0; e < 8; ++e) {
    int c = l * 8 + e;
    ov[e] = (short)f2bf((v[e] - mean) * rs * lng[c] + lnb[c]);
  }
  *(bf16x8*)(xn + (size_t)row * 512 + l * 8) = ov;
}

// plain LayerNorm rows of h (f32) -> bf16. 1 wave per row.
__global__ __launch_bounds__(256) void ln_rows(
    const float* __restrict__ in, const float* __restrict__ gg,
    const float* __restrict__ bb, u16* __restrict__ out) {
  const int row = blockIdx.x * 4 + (threadIdx.x >> 6);
  const int l = threadIdx.x & 63;
  const float* p = in + (size_t)row * 512 + l * 8;
  float4 a4 = *(const float4*)p;
  float4 b4 = *(const float4*)(p + 4);
  float v[8] = {a4.x, a4.y, a4.z, a4.w, b4.x, b4.y, b4.z, b4.w};
  float s = 0.f, q = 0.f;
#pragma unroll
  for (int e = 0; e < 8; ++e) { s += v[e]; q += v[e] * v[e]; }
#pragma unroll
  for (int d = 1; d < 64; d <<= 1) { s += __shfl_xor(s, d); q += __shfl_xor(q, d); }
  float mean = s * (1.f / 512.f);
  float rs = rsqrtf(q * (1.f / 512.f) - mean * mean + 1e-5f);
  bf16x8 ov;
#pragma unroll
  for (int e = 0; e < 8; ++e) {
    int c = l * 8 + e;
    ov[e] = (short)f2bf((v[e] - mean) * rs * gg[c] + bb[c]);
  }
  *(bf16x8*)(out + (size_t)row * 512 + l * 8) = ov;
}

// weight convert: f32 (K x N) row-major -> bf16 (N x K) row-major, per layer y
__global__ __launch_bounds__(256) void cvt_wt(
    const float* __restrict__ src, u16* __restrict__ dst, int N, int kshift,
    size_t src_lstride, size_t dst_lstride) {
  src += blockIdx.y * src_lstride;
  dst += blockIdx.y * dst_lstride;
  int idx = blockIdx.x * 256 + threadIdx.x;
  int K = 1 << kshift;
  int n = idx >> kshift;
  int k = idx & (K - 1);
  if (n >= N) return;
  dst[idx] = f2bf(src[(size_t)k * N + n]);
}

__global__ void pack_qkv_bias(const float* __restrict__ bq, const float* __restrict__ bk,
                              const float* __restrict__ bv, float* __restrict__ dst) {
  int lyr = blockIdx.y;
  int i = blockIdx.x * 256 + threadIdx.x;
  if (i < 512) dst[lyr * 1536 + i] = bq[lyr * 512 + i];
  else if (i < 1024) dst[lyr * 1536 + i] = bk[lyr * 512 + i - 512];
  else if (i < 1536) dst[lyr * 1536 + i] = bv[lyr * 512 + i - 1024];
}

// pos table: pk[r][d] = clip(pe_k[r + 6977][d], +-5) for r = j-i+1023 in [0,2047)
__global__ void cvt_pk(const float* __restrict__ pe, u16* __restrict__ pkb) {
  int i = blockIdx.x * 256 + threadIdx.x;
  if (i >= 2047 * 64) return;
  float v = pe[i + 6977 * 64];
  v = fminf(fmaxf(v, -5.f), 5.f);
  pkb[i] = f2bf(v);
}

// V transpose: qkv v-section (B*T, 512) -> vT[(b*8+h)*64 + d][t]
__global__ __launch_bounds__(256) void transpV(
    const u16* __restrict__ qkv, u16* __restrict__ vT) {
  __shared__ short tile[64][72];
  const int tid = threadIdx.x;
  const int tt = blockIdx.x, bh = blockIdx.y;
  const int b = bh >> 3, h = bh & 7;
#pragma unroll
  for (int rr = 0; rr < 2; ++rr) {
    int trow = rr * 32 + (tid >> 3);
    bf16x8 v = *(const bf16x8*)(qkv + (size_t)(b * 1024 + tt * 64 + trow) * 1536 +
                                1024 + h * 64 + (tid & 7) * 8);
#pragma unroll
    for (int e = 0; e < 8; ++e) tile[trow][(tid & 7) * 8 + e] = v[e];
  }
  __syncthreads();
#pragma unroll
  for (int rr = 0; rr < 2; ++rr) {
    int d = rr * 32 + (tid >> 3);
    bf16x8 ov;
#pragma unroll
    for (int e = 0; e < 8; ++e) ov[e] = tile[(tid & 7) * 8 + e][d];
    *(bf16x8*)(vT + ((size_t)bh * 64 + d) * 1024 + tt * 64 + (tid & 7) * 8) = ov;
  }
}

// ---------------- GEMM: C(MxN) = A(MxK,bf16) @ W^T(NxK,bf16) + epilogue ------
// 128xBN tile (BN=128 or 64), BK=32, 4 waves, 16x16x32 MFMA, double-buffered
// global_load_lds. BN=128: waves 2x2 over 64x64; BN=64: waves 2x2 over 64x32.
// EPI: 0 = bf16 out (+bias, Q-section cols<512 pre-scaled by 0.125);
//      1 = bf16 relu out; 2 = f32 resid + v*scale; 3 = f32 resid + v
template <int EPI, int BN>
__global__ __launch_bounds__(256) void gemm128(
    const u16* __restrict__ A, const u16* __restrict__ Wt,
    const float* __restrict__ bias, const float* __restrict__ scl,
    const float* __restrict__ resid, float* __restrict__ outf,
    u16* __restrict__ outb, int N, int K) {
  constexpr int NI = BN >> 5;          // col-fragments per wave (4 or 2)
  __shared__ __attribute__((aligned(16))) u16 As[2][128 * 32];
  __shared__ __attribute__((aligned(16))) u16 Bs[2][BN * 32];
  const int tid = threadIdx.x;
  const int l = tid & 63, w = tid >> 6;
  const int g = l >> 4, r = l & 15;
  const int wr = w >> 1, wc = w & 1;
  const int m0 = blockIdx.y * 128, n0 = blockIdx.x * BN;

  const f32x4 fz = {0.f, 0.f, 0.f, 0.f};
  f32x4 acc[4][NI];
#pragma unroll
  for (int i = 0; i < 4; ++i)
#pragma unroll
    for (int j = 0; j < NI; ++j) acc[i][j] = fz;

  const int nkt = K >> 5;
  const int arow = tid >> 2, acol = (tid & 3) * 8;
  const u16* aG = A + (size_t)(m0 + arow) * K + acol;
  const u16* bG = Wt + (size_t)(n0 + arow) * K + acol;

  auto stage = [&](int kt, int buf) {
    const u16* ga = aG + kt * 32;
    const u16* gb = bG + kt * 32;
    u16* la = &As[buf][tid * 8];
    u16* lb = &Bs[buf][tid * 8];
    GLD16(ga, la);
    GLD16(ga + (size_t)64 * K, la + 2048);
    GLD16(gb, lb);
    if constexpr (BN == 128) GLD16(gb + (size_t)64 * K, lb + 2048);
  };

  stage(0, 0);
  __syncthreads();
  for (int kt = 0; kt < nkt; ++kt) {
    const int cb = kt & 1;
    if (kt + 1 < nkt) stage(kt + 1, cb ^ 1);
    bf16x8 af[4], bfr[NI];
#pragma unroll
    for (int mi = 0; mi < 4; ++mi)
      af[mi] = *(const bf16x8*)&As[cb][(wr * 64 + mi * 16 + r) * 32 + g * 8];
#pragma unroll
    for (int ni = 0; ni < NI; ++ni)
      bfr[ni] = *(const bf16x8*)&Bs[cb][(wc * (BN / 2) + ni * 16 + r) * 32 + g * 8];
#pragma unroll
    for (int mi = 0; mi < 4; ++mi)
#pragma unroll
      for (int ni = 0; ni < NI; ++ni)
        acc[mi][ni] = __builtin_amdgcn_mfma_f32_16x16x32_bf16(
            af[mi], bfr[ni], acc[mi][ni], 0, 0, 0);
    __syncthreads();   // drains vmcnt(0): next tile staged, cur reads done
  }

#pragma unroll
  for (int mi = 0; mi < 4; ++mi)
#pragma unroll
    for (int ni = 0; ni < NI; ++ni)
#pragma unroll
      for (int reg = 0; reg < 4; ++reg) {
        int gm = m0 + wr * 64 + mi * 16 + g * 4 + reg;
        int gn = n0 + wc * (BN / 2) + ni * 16 + r;
        float v = acc[mi][ni][reg] + bias[gn];
        size_t oi = (size_t)gm * N + gn;
        if constexpr (EPI == 0) outb[oi] = f2bf(gn < 512 ? v * 0.125f : v);
        else if constexpr (EPI == 1) outb[oi] = f2bf(fmaxf(v, 0.f));
        else if constexpr (EPI == 2) outf[oi] = resid[oi] + v * scl[gn];
        else outf[oi] = resid[oi] + v;
      }
}

// ---------------- fused flash attention with relative-position bias ---------
// 4 waves, one (b,h, 64-row i-block); 16 j-tiles of 64. LDS = 40KB (4 blk/CU).
// Rel-pos M is computed in 64-col chunks: window advances 64/tile, so chunk
// jt+1 is computed each tile (4 MFMAs) and chunk jt is reused from the
// previous tile. Two 8KB regions ping-pong as {Pk stage -> chunk home}.
// Q arrives pre-scaled by 1/sqrt(dk) from the QKV GEMM epilogue.
__global__ __launch_bounds__(256, 4) void attn64(
    const u16* __restrict__ qkv, const u16* __restrict__ vT,
    const u16* __restrict__ pkb, u16* __restrict__ o) {
  __shared__ __attribute__((aligned(16))) u16 lds[20480];   // 40 KB
  u16* Kt  = lds;              // [64][64] swizzled (8 KB)
  u16* Vtt = lds + 4096;       // [64][64] swizzled (8 KB)  V^T: [d][j]
  u16* Rb0 = lds + 8192;       // 8 KB: Pk stage (swz) then M chunk (linear)
  u16* Rb1 = lds + 12288;      // 8 KB: ping-pong partner
  u16* Pt  = lds + 16384;      // [64][64] swizzled (8 KB)

  const int tid = threadIdx.x, l = tid & 63, w = tid >> 6;
  const int g = l >> 4, r = l & 15;
  const int iblk = blockIdx.x, bh = blockIdx.y;
  const int b = bh >> 3, h = bh & 7;
  const int i0 = iblk * 64;
  const int relbase = 960 - i0;        // abs pk row of chunk 0, always >= 0
  const int iw = w * 16 + g * 4;       // own C/D row base (+reg)

  // Q fragments straight from global (pre-scaled; reused across all 16 tiles)
  bf16x8 aq[2];
  {
    const u16* qp = qkv + (size_t)(b * 1024 + i0 + w * 16 + r) * 1536 + h * 64 + g * 8;
    aq[0] = *(const bf16x8*)(qp);
    aq[1] = *(const bf16x8*)(qp + 32);
  }

  const f32x4 fz = {0.f, 0.f, 0.f, 0.f};

  // ---- prologue: M chunk 0 -> Rb0 ----
  {
#pragma unroll
    for (int rr = 0; rr < 2; ++rr) {
      int row = rr * 32 + (tid >> 3);
      int colb = ((tid & 7) * 16) ^ ((row & 7) << 4);
      int gr = relbase + row;
      gr = gr > 2046 ? 2046 : gr;
      GLD16(pkb + (size_t)gr * 64 + (colb >> 1), Rb0 + rr * 2048 + tid * 8);
    }
    __syncthreads();
    f32x4 mac[4];
#pragma unroll
    for (int mf = 0; mf < 4; ++mf) {
      mac[mf] = fz;
#pragma unroll
      for (int ks = 0; ks < 2; ++ks) {
        int row = mf * 16 + r;
        int colb = (ks * 64 + g * 16) ^ ((row & 7) << 4);
        bf16x8 bp = *(const bf16x8*)(Rb0 + row * 64 + (colb >> 1));
        mac[mf] = __builtin_amdgcn_mfma_f32_16x16x32_bf16(aq[ks], bp, mac[mf], 0, 0, 0);
      }
    }
    __syncthreads();   // all waves done reading Rb0-as-Pk
#pragma unroll
    for (int mf = 0; mf < 4; ++mf)
#pragma unroll
      for (int reg = 0; reg < 4; ++reg)
        Rb0[(iw + reg) * 64 + mf * 16 + r] = f2bf(mac[mf][reg]);
  }

  float mrow[4], lpart[4];
  f32x4 oacc[4];
#pragma unroll
  for (int i = 0; i < 4; ++i) { mrow[i] = -1e30f; lpart[i] = 0.f; oacc[i] = fz; }

  for (int jt = 0; jt < 16; ++jt) {
    u16* Rcur  = (jt & 1) ? Rb0 : Rb1;   // will hold chunk jt+1
    u16* Rprev = (jt & 1) ? Rb1 : Rb0;   // holds chunk jt
    const int j0 = jt * 64;
    {
      const u16* kg = qkv + (size_t)(b * 1024 + j0) * 1536 + 512 + h * 64;
      const u16* vg = vT + (size_t)bh * 65536 + j0;
      const int gbase = relbase + 64 * (jt + 1);
#pragma unroll
      for (int rr = 0; rr < 2; ++rr) {
        int row = rr * 32 + (tid >> 3);
        int colb = ((tid & 7) * 16) ^ ((row & 7) << 4);
        GLD16(kg + (size_t)row * 1536 + (colb >> 1), Kt + rr * 2048 + tid * 8);
        GLD16(vg + (size_t)row * 1024 + (colb >> 1), Vtt + rr * 2048 + tid * 8);
        int gr = gbase + row;
        gr = gr > 2046 ? 2046 : gr;
        GLD16(pkb + (size_t)gr * 64 + (colb >> 1), Rcur + rr * 2048 + tid * 8);
      }
    }
    __syncthreads();   // bar1: staged K/V/Pk visible

    // QK^T (Q pre-scaled)
    f32x4 sacc[4];
#pragma unroll
    for (int cf = 0; cf < 4; ++cf) sacc[cf] = fz;
#pragma unroll
    for (int ks = 0; ks < 2; ++ks)
#pragma unroll
      for (int cf = 0; cf < 4; ++cf) {
        int row = cf * 16 + r;
        int colb = (ks * 64 + g * 16) ^ ((row & 7) << 4);
        bf16x8 bk = *(const bf16x8*)(Kt + row * 64 + (colb >> 1));
        sacc[cf] = __builtin_amdgcn_mfma_f32_16x16x32_bf16(aq[ks], bk, sacc[cf], 0, 0, 0);
      }

    // M chunk jt+1 = Q @ Pk^T (4 MFMAs), accumulators in registers
    f32x4 mac[4];
#pragma unroll
    for (int mf = 0; mf < 4; ++mf) {
      mac[mf] = fz;
#pragma unroll
      for (int ks = 0; ks < 2; ++ks) {
        int row = mf * 16 + r;
        int colb = (ks * 64 + g * 16) ^ ((row & 7) << 4);
        bf16x8 bp = *(const bf16x8*)(Rcur + row * 64 + (colb >> 1));
        mac[mf] = __builtin_amdgcn_mfma_f32_16x16x32_bf16(aq[ks], bp, mac[mf], 0, 0, 0);
      }
    }
    __syncthreads();   // bar2: all waves done reading Rcur-as-Pk (and Kt QK reads)

    // write chunk jt+1 into Rcur (linear [row][col]; wave-private rows)
#pragma unroll
    for (int mf = 0; mf < 4; ++mf)
#pragma unroll
      for (int reg = 0; reg < 4; ++reg)
        Rcur[(iw + reg) * 64 + mf * 16 + r] = f2bf(mac[mf][reg]);

    // S assembly (gather from two chunks) + online softmax
    float sv[4][4], pmax[4];
#pragma unroll
    for (int reg = 0; reg < 4; ++reg) pmax[reg] = -1e30f;
#pragma unroll
    for (int cf = 0; cf < 4; ++cf)
#pragma unroll
      for (int reg = 0; reg < 4; ++reg) {
        int iir = iw + reg;
        int c63 = cf * 16 + r - iir + 63;          // in [0,126]
        const u16* src = (c63 < 64) ? (Rprev + iir * 64 + c63)
                                    : (Rcur + iir * 64 + c63 - 64);
        float s = sacc[cf][reg] + bf2f(*src);
        sv[cf][reg] = s;
        pmax[reg] = fmaxf(pmax[reg], s);
      }
#pragma unroll
    for (int d = 1; d < 16; d <<= 1)
#pragma unroll
      for (int reg = 0; reg < 4; ++reg)
        pmax[reg] = fmaxf(pmax[reg], __shfl_xor(pmax[reg], d));
#pragma unroll
    for (int reg = 0; reg < 4; ++reg) {
      float mnew = fmaxf(mrow[reg], pmax[reg]);
      float corr = __expf(mrow[reg] - mnew);
      mrow[reg] = mnew;
      lpart[reg] *= corr;
#pragma unroll
      for (int df = 0; df < 4; ++df) oacc[df][reg] *= corr;
      float ps = 0.f;
      int ii = iw + reg;
#pragma unroll
      for (int cf = 0; cf < 4; ++cf) {
        float p = __expf(sv[cf][reg] - mnew);
        ps += p;
        int jj = cf * 16 + r;
        int colb = (jj * 2) ^ ((ii & 7) << 4);
        Pt[ii * 64 + (colb >> 1)] = f2bf(p);
      }
      lpart[reg] += ps;
    }

    // PV: O += P @ V  (A from Pt, B from V^T; wave-private P rows)
#pragma unroll
    for (int ks = 0; ks < 2; ++ks) {
      int prow = w * 16 + r;
      int pcolb = (ks * 64 + g * 16) ^ ((prow & 7) << 4);
      bf16x8 ap = *(const bf16x8*)(Pt + prow * 64 + (pcolb >> 1));
#pragma unroll
      for (int df = 0; df < 4; ++df) {
        int vrow = df * 16 + r;
        int vcolb = (ks * 64 + g * 16) ^ ((vrow & 7) << 4);
        bf16x8 bv = *(const bf16x8*)(Vtt + vrow * 64 + (vcolb >> 1));
        oacc[df] = __builtin_amdgcn_mfma_f32_16x16x32_bf16(ap, bv, oacc[df], 0, 0, 0);
      }
    }
    __syncthreads();   // bar3: Kt/Vtt/Rprev reads done before next stage
  }

#pragma unroll
  for (int d = 1; d < 16; d <<= 1)
#pragma unroll
    for (int reg = 0; reg < 4; ++reg) lpart[reg] += __shfl_xor(lpart[reg], d);
#pragma unroll
  for (int reg = 0; reg < 4; ++reg) {
    float inv = 1.f / lpart[reg];
    int ii = iw + reg;
#pragma unroll
    for (int df = 0; df < 4; ++df)
      o[(size_t)(b * 1024 + i0 + ii) * 512 + h * 64 + df * 16 + r] =
          f2bf(oacc[df][reg] * inv);
  }
}

// ---------------------------------------------------------------------------
extern "C" void kernel_launch(void* const* d_in, const int* in_sizes, int n_in,
                              void* d_out, int out_size, void* d_ws, size_t ws_size,
                              hipStream_t stream) {
  (void)in_sizes; (void)n_in; (void)out_size;
  const float* x      = (const float*)d_in[0];
  const float* conv_w = (const float*)d_in[1];
  const float* conv_b = (const float*)d_in[2];
  const float* gn_g   = (const float*)d_in[3];
  const float* gn_b   = (const float*)d_in[4];
  const float* pe_k   = (const float*)d_in[5];
  const float* ln1_g  = (const float*)d_in[6];
  const float* ln1_b  = (const float*)d_in[7];
  const float* wq     = (const float*)d_in[8];
  const float* bq     = (const float*)d_in[9];
  const float* wk     = (const float*)d_in[10];
  const float* bk     = (const float*)d_in[11];
  const float* wv     = (const float*)d_in[12];
  const float* bv     = (const float*)d_in[13];
  const float* wo     = (const float*)d_in[14];
  const float* bo     = (const float*)d_in[15];
  const float* lsc    = (const float*)d_in[16];
  const float* ln2_g  = (const float*)d_in[17];
  const float* ln2_b  = (const float*)d_in[18];
  const float* w1     = (const float*)d_in[19];
  const float* b1     = (const float*)d_in[20];
  const float* w2     = (const float*)d_in[21];
  const float* b2     = (const float*)d_in[22];

  char* ws = (char*)d_ws;
  size_t off = 0;
  auto alloc = [&](size_t bytes) {
    char* p = ws + off;
    off = (off + bytes + 255) & ~(size_t)255;
    return p;
  };
  float* hbuf  = (float*)alloc((size_t)8192 * 512 * 4);
  u16* xn      = (u16*)alloc((size_t)8192 * 512 * 2);
  u16* qkvb    = (u16*)alloc((size_t)8192 * 1536 * 2);
  u16* vTb     = (u16*)alloc((size_t)64 * 64 * 1024 * 2);
  u16* ob      = (u16*)alloc((size_t)8192 * 512 * 2);
  u16* f1      = (u16*)alloc((size_t)8192 * 2048 * 2);
  float* stats = (float*)alloc(256);
  u16* wqkvb   = (u16*)alloc((size_t)2 * 1536 * 512 * 2);
  u16* wob     = (u16*)alloc((size_t)2 * 512 * 512 * 2);
  u16* w1b     = (u16*)alloc((size_t)2 * 2048 * 512 * 2);
  u16* w2b     = (u16*)alloc((size_t)2 * 512 * 2048 * 2);
  float* bqkv  = (float*)alloc(2 * 1536 * 4);
  u16* pkbuf   = (u16*)alloc(2047 * 64 * 2);
  if (off > ws_size) return;   // workspace too small -> clean validation fail
  // convb is only live before the layer loop; alias it onto f1 (32 MB >= 16 MB)
  float* convb = (float*)f1;

  hipMemsetAsync(stats, 0, 64, stream);

  // weight/bias converts (layer dim = blockIdx.y)
  cvt_wt<<<dim3(1024, 2), 256, 0, stream>>>(wq, wqkvb, 512, 9, 262144, 786432);
  cvt_wt<<<dim3(1024, 2), 256, 0, stream>>>(wk, wqkvb + 262144, 512, 9, 262144, 786432);
  cvt_wt<<<dim3(1024, 2), 256, 0, stream>>>(wv, wqkvb + 524288, 512, 9, 262144, 786432);
  cvt_wt<<<dim3(1024, 2), 256, 0, stream>>>(wo, wob, 512, 9, 262144, 262144);
  cvt_wt<<<dim3(4096, 2), 256, 0, stream>>>(w1, w1b, 2048, 9, 1048576, 1048576);
  cvt_wt<<<dim3(4096, 2), 256, 0, stream>>>(w2, w2b, 512, 11, 1048576, 1048576);
  pack_qkv_bias<<<dim3(6, 2), 256, 0, stream>>>(bq, bk, bv, bqkv);
  cvt_pk<<<512, 256, 0, stream>>>(pe_k, pkbuf);

  conv_front<<<16384, 256, 0, stream>>>(x, conv_w, conv_b, convb);
  gn_stats<<<dim3(64, 8), 256, 0, stream>>>(convb, stats);
  gn_ln<<<2048, 256, 0, stream>>>(convb, stats, gn_g, gn_b, ln1_g, ln1_b, hbuf, xn);

  for (int lyr = 0; lyr < 2; ++lyr) {
    gemm128<0, 128><<<dim3(12, 64), 256, 0, stream>>>(
        xn, wqkvb + (size_t)lyr * 786432, bqkv + lyr * 1536,
        nullptr, nullptr, nullptr, qkvb, 1536, 512);
    transpV<<<dim3(16, 64), 256, 0, stream>>>(qkvb, vTb);
    attn64<<<dim3(16, 64), 256, 0, stream>>>(qkvb, vTb, pkbuf, ob);
    gemm128<2, 64><<<dim3(8, 64), 256, 0, stream>>>(
        ob, wob + (size_t)lyr * 262144, bo + lyr * 512,
        lsc + lyr * 512, hbuf, hbuf, nullptr, 512, 512);
    ln_rows<<<2048, 256, 0, stream>>>(hbuf, ln2_g + lyr * 512, ln2_b + lyr * 512, xn);
    gemm128<1, 128><<<dim3(16, 64), 256, 0, stream>>>(
        xn, w1b + (size_t)lyr * 1048576, b1 + lyr * 2048,
        nullptr, nullptr, nullptr, f1, 2048, 512);
    float* outp = (lyr == 1) ? (float*)d_out : hbuf;
    gemm128<3, 64><<<dim3(8, 64), 256, 0, stream>>>(
        f1, w2b + (size_t)lyr * 1048576, b2 + lyr * 512,
        nullptr, hbuf, outp, nullptr, 512, 2048);
    if (lyr == 0)
      ln_rows<<<2048, 256, 0, stream>>>(hbuf, ln1_g + 512, ln1_b + 512, xn);
  }
}